// Round 1
// baseline (480.738 us; speedup 1.0000x reference)
//
#include <hip/hip_runtime.h>
#include <math.h>

#define BB 8
#define SS 2048
#define DD 64
#define BKT 64              // keys per LDS tile
#define NT  (SS / BKT)      // 32 tiles
#define NEGC (-1e9f)

// One block: 64 queries x all 2048 keys (flash / online softmax).
// Thread t: query qi = t>>2, dim-quarter p = t&3 (16 dims each).
// Score dot is split across the 4 lanes of a query, combined via shfl_xor.
__global__ __launch_bounds__(256, 1)
void attn_fwd(const float* __restrict__ Q, const float* __restrict__ K,
              const float* __restrict__ V, const float* __restrict__ MQ,
              const float* __restrict__ MK, const float* __restrict__ MV,
              float* __restrict__ O) {
    __shared__ float Ks[BKT * DD];
    __shared__ float Vs[BKT * DD];
    __shared__ float MKs[BKT];

    const int t  = threadIdx.x;
    const int qi = t >> 2;
    const int p  = t & 3;
    const int b  = blockIdx.x >> 5;          // 32 q-tiles per batch
    const int qrow = (blockIdx.x & 31) * 64 + qi;

    const float* Kb  = K  + (size_t)b * SS * DD;
    const float* Vb  = V  + (size_t)b * SS * DD;
    const float* MKb = MK + (size_t)b * SS;
    const float* MVb = MV + (size_t)b * SS;

    // Load this thread's 16 query dims, pre-scaled by 1/sqrt(D)
    float qv[16];
    {
        const float* Qr = Q + ((size_t)b * SS + qrow) * DD + p * 16;
        const float sc = 0.125f;
#pragma unroll
        for (int u = 0; u < 4; u++) {
            float4 tmp = ((const float4*)Qr)[u];
            qv[4*u+0] = tmp.x * sc; qv[4*u+1] = tmp.y * sc;
            qv[4*u+2] = tmp.z * sc; qv[4*u+3] = tmp.w * sc;
        }
    }
    const float mq = MQ[(size_t)b * SS + qrow];

    float m = -1e30f;
    float l = 0.0f;
    float ov[16];
#pragma unroll
    for (int d = 0; d < 16; d++) ov[d] = 0.0f;

    // ---- stage tile 0 into LDS ----
    float4 kp[4], vp[4];
    float  mvp[4];
    float  mkp = 1.0f;
#pragma unroll
    for (int u = 0; u < 4; u++) {
        int f = t + 256 * u;                 // float4 index into 64x64 tile
        kp[u]  = ((const float4*)Kb)[f];
        vp[u]  = ((const float4*)Vb)[f];
        mvp[u] = MVb[f >> 4];
    }
    if (t < BKT) mkp = MKb[t];
#pragma unroll
    for (int u = 0; u < 4; u++) {
        int f = t + 256 * u;
        float4 vv = vp[u];
        float mvv = mvp[u];
        vv.x *= mvv; vv.y *= mvv; vv.z *= mvv; vv.w *= mvv;
        ((float4*)Ks)[f] = kp[u];
        ((float4*)Vs)[f] = vv;
    }
    if (t < BKT) MKs[t] = mkp;
    __syncthreads();

#pragma unroll 1
    for (int tile = 0; tile < NT; tile++) {
        // ---- prefetch next tile into registers (hides HBM latency) ----
        if (tile + 1 < NT) {
            const float* ksrc = Kb + (size_t)(tile + 1) * BKT * DD;
            const float* vsrc = Vb + (size_t)(tile + 1) * BKT * DD;
#pragma unroll
            for (int u = 0; u < 4; u++) {
                int f = t + 256 * u;
                kp[u]  = ((const float4*)ksrc)[f];
                vp[u]  = ((const float4*)vsrc)[f];
                mvp[u] = MVb[(size_t)(tile + 1) * BKT + (f >> 4)];
            }
            if (t < BKT) mkp = MKb[(size_t)(tile + 1) * BKT + t];
        }

        // ---- compute on current LDS tile, in 16-key chunks ----
#pragma unroll 1
        for (int c = 0; c < 4; c++) {
            const int j0 = c * 16;
            float s[16];
            float cmax = -1e30f;
#pragma unroll
            for (int jj = 0; jj < 16; jj++) {
                const float* kr = &Ks[(j0 + jj) * DD + p * 16];
                float acc0 = 0.0f, acc1 = 0.0f;
#pragma unroll
                for (int u = 0; u < 2; u++) {
                    float4 kx = ((const float4*)kr)[u];
                    acc0 = fmaf(qv[4*u+0], kx.x, acc0);
                    acc0 = fmaf(qv[4*u+1], kx.y, acc0);
                    acc0 = fmaf(qv[4*u+2], kx.z, acc0);
                    acc0 = fmaf(qv[4*u+3], kx.w, acc0);
                }
#pragma unroll
                for (int u = 2; u < 4; u++) {
                    float4 kx = ((const float4*)kr)[u];
                    acc1 = fmaf(qv[4*u+0], kx.x, acc1);
                    acc1 = fmaf(qv[4*u+1], kx.y, acc1);
                    acc1 = fmaf(qv[4*u+2], kx.z, acc1);
                    acc1 = fmaf(qv[4*u+3], kx.w, acc1);
                }
                float acc = acc0 + acc1;
                acc += __shfl_xor(acc, 1);
                acc += __shfl_xor(acc, 2);
                float mk = MKs[j0 + jj];
                float sv = acc + (1.0f - mq * mk) * NEGC;
                s[jj] = sv;
                cmax  = fmaxf(cmax, sv);
            }
            float nm    = fmaxf(m, cmax);
            float alpha = __expf(m - nm);
            m = nm;
            l *= alpha;
#pragma unroll
            for (int d = 0; d < 16; d++) ov[d] *= alpha;
#pragma unroll
            for (int jj = 0; jj < 16; jj++) {
                float pj = __expf(s[jj] - m);
                l += pj;
                const float* vr = &Vs[(j0 + jj) * DD + p * 16];
#pragma unroll
                for (int u = 0; u < 4; u++) {
                    float4 vx = ((const float4*)vr)[u];
                    ov[4*u+0] = fmaf(pj, vx.x, ov[4*u+0]);
                    ov[4*u+1] = fmaf(pj, vx.y, ov[4*u+1]);
                    ov[4*u+2] = fmaf(pj, vx.z, ov[4*u+2]);
                    ov[4*u+3] = fmaf(pj, vx.w, ov[4*u+3]);
                }
            }
        }

        __syncthreads();   // everyone done reading LDS
        if (tile + 1 < NT) {
#pragma unroll
            for (int u = 0; u < 4; u++) {
                int f = t + 256 * u;
                float4 vv = vp[u];
                float mvv = mvp[u];
                vv.x *= mvv; vv.y *= mvv; vv.z *= mvv; vv.w *= mvv;
                ((float4*)Ks)[f] = kp[u];
                ((float4*)Vs)[f] = vv;
            }
            if (t < BKT) MKs[t] = mkp;
            __syncthreads();   // stores visible before next compute
        }
    }

    const float inv = 1.0f / l;
    float* Or = O + ((size_t)b * SS + qrow) * DD + p * 16;
#pragma unroll
    for (int u = 0; u < 4; u++) {
        float4 w;
        w.x = ov[4*u+0] * inv; w.y = ov[4*u+1] * inv;
        w.z = ov[4*u+2] * inv; w.w = ov[4*u+3] * inv;
        ((float4*)Or)[u] = w;
    }
}

extern "C" void kernel_launch(void* const* d_in, const int* in_sizes, int n_in,
                              void* d_out, int out_size, void* d_ws, size_t ws_size,
                              hipStream_t stream) {
    const float* Q  = (const float*)d_in[0];
    const float* K  = (const float*)d_in[1];
    const float* V  = (const float*)d_in[2];
    const float* MQ = (const float*)d_in[3];
    const float* MK = (const float*)d_in[4];
    const float* MV = (const float*)d_in[5];
    float* O = (float*)d_out;

    dim3 grid(BB * (SS / 64));   // 256 blocks: 64 queries each
    dim3 block(256);
    attn_fwd<<<grid, block, 0, stream>>>(Q, K, V, MQ, MK, MV, O);
}

// Round 2
// 136.401 us; speedup vs baseline: 3.5244x; 3.5244x over previous
//
#include <hip/hip_runtime.h>
#include <math.h>

#define BATCH 8
#define SEQ   2048
#define DIM   64
#define NEGC  (-1e9f)

typedef short short8 __attribute__((ext_vector_type(8)));
typedef float f32x4  __attribute__((ext_vector_type(4)));

#define MFMA(a, b, c) __builtin_amdgcn_mfma_f32_16x16x32_bf16((a), (b), (c), 0, 0, 0)

__device__ __forceinline__ ushort f2bf(float x) {   // fp32 -> bf16 bits, RNE
    uint u = __float_as_uint(x);
    uint r = (u + 0x7fffu + ((u >> 16) & 1u)) >> 16;
    return (ushort)r;
}
__device__ __forceinline__ float bf2f(ushort h) {
    return __uint_as_float(((uint)h) << 16);
}

// Sᵀ = K·Qᵀ (rows=keys, cols=queries) so softmax cols live in-lane.
// Oᵀ = Vᵀ·Pᵀ. Verified gfx950 16x16x32 layouts:
//   A[m=lane&15][k=(lane>>4)*8+j], B[n=lane&15][k=(lane>>4)*8+j],
//   C/D col=lane&15, row=(lane>>4)*4+reg.
__global__ __launch_bounds__(512, 2)
void attn_mfma(const float* __restrict__ Q, const float* __restrict__ K,
               const float* __restrict__ V, const float* __restrict__ MQ,
               const float* __restrict__ MK, const float* __restrict__ MV,
               float* __restrict__ O) {
    // K tile (64 keys x 64 d) hi/lo bf16, fragment-interleaved:
    //   idx = ((mt*2+c)*64 + quad_d*16 + (key&15))*8 + (d&7),  mt=key>>4, c=d>>5
    __shared__ __align__(16) ushort KfH[4096];
    __shared__ __align__(16) ushort KfL[4096];
    // V tile transposed, fragment-interleaved for A-operand of PV:
    //   idx = (((k>>5)*4 + (d>>4))*64 + ((k>>3)&3)*16 + (d&15))*8 + (k&7)
    __shared__ __align__(16) ushort Vf[4096];
    __shared__ __align__(16) float  MKs[64];
    __shared__ __align__(16) ushort Pf[8][512];   // per-wave Pᵀ scratch (32k x 16q)
    __shared__ __align__(16) float  Msc[4][1280]; // split-K merge scratch

    const int t    = threadIdx.x;
    const int w    = t >> 6;
    const int lane = t & 63;
    const int quad = lane >> 4;
    const int lq   = lane & 15;
    const int qg   = w & 3;    // query group (16 queries)
    const int half = w >> 2;   // key-half within each staged 64-key tile

    const int b  = blockIdx.x >> 5;
    const int q0 = (blockIdx.x & 31) * 64;
    const int q  = q0 + qg * 16 + lq;

    const float* Kb  = K  + (size_t)b * SEQ * DIM;
    const float* Vb  = V  + (size_t)b * SEQ * DIM;
    const float* MKb = MK + (size_t)b * SEQ;
    const float* MVb = MV + (size_t)b * SEQ;

    // ---- preload Q fragments (B-operand layout), hi/lo, pre-scaled by 1/8 ----
    short8 qh[2], ql[2];
    {
        const float* Qr = Q + ((size_t)b * SEQ + q) * DIM;
#pragma unroll
        for (int c = 0; c < 2; c++) {
            float4 x0 = *(const float4*)(Qr + c * 32 + quad * 8);
            float4 x1 = *(const float4*)(Qr + c * 32 + quad * 8 + 4);
            float xs[8] = {x0.x, x0.y, x0.z, x0.w, x1.x, x1.y, x1.z, x1.w};
#pragma unroll
            for (int j = 0; j < 8; j++) {
                float v = xs[j] * 0.125f;
                ushort hi = f2bf(v);
                ushort lo = f2bf(v - bf2f(hi));
                qh[c][j] = (short)hi;
                ql[c][j] = (short)lo;
            }
        }
    }
    const float mq   = MQ[(size_t)b * SEQ + q];
    const float apen = NEGC * mq;

    float m = -1e30f, l = 0.0f;
    f32x4 ot0 = {0,0,0,0}, ot1 = {0,0,0,0}, ot2 = {0,0,0,0}, ot3 = {0,0,0,0};

    ushort* Pw   = Pf[w];
    const int kb = half * 32;       // this wave's key offset within staged tile

#pragma unroll 1
    for (int tile = 0; tile < 32; tile++) {
        const int k0 = tile * 64;
        // ---------------- stage 64 keys of K (hi/lo) and Vᵀ ----------------
#pragma unroll
        for (int u = 0; u < 2; u++) {
            int f   = t + 512 * u;         // float4 index within 64x64 tile
            int key = f >> 4;
            int dp  = (f & 15) * 4;
            float4 kx = *(const float4*)(Kb + (size_t)k0 * DIM + (size_t)f * 4);
            float4 vx = *(const float4*)(Vb + (size_t)k0 * DIM + (size_t)f * 4);
            float  mv = MVb[k0 + key];

            int mt = key >> 4, mm = key & 15, c = dp >> 5, qd = (dp >> 3) & 3, j0 = dp & 7;
            int kbase = ((mt * 2 + c) * 64 + qd * 16 + mm) * 8 + j0;
            float xk[4] = {kx.x, kx.y, kx.z, kx.w};
            ushort hs[4], ls[4];
#pragma unroll
            for (int i = 0; i < 4; i++) {
                hs[i] = f2bf(xk[i]);
                ls[i] = f2bf(xk[i] - bf2f(hs[i]));
            }
            *(ushort4*)&KfH[kbase] = make_ushort4(hs[0], hs[1], hs[2], hs[3]);
            *(ushort4*)&KfL[kbase] = make_ushort4(ls[0], ls[1], ls[2], ls[3]);

            float xv[4] = {vx.x * mv, vx.y * mv, vx.z * mv, vx.w * mv};
#pragma unroll
            for (int i = 0; i < 4; i++) {
                int d = dp + i;
                int vidx = (((key >> 5) * 4 + (d >> 4)) * 64 + ((key >> 3) & 3) * 16 + (d & 15)) * 8 + (key & 7);
                Vf[vidx] = f2bf(xv[i]);
            }
        }
        if (t < 64) MKs[t] = MKb[k0 + t];
        __syncthreads();

        // ---------------- one 32-key MFMA step (this wave's half) ----------------
        f32x4 st0 = {0,0,0,0}, st1 = {0,0,0,0};
        const int mtg = half * 2;
#pragma unroll
        for (int c = 0; c < 2; c++) {
            short8 a0h = *(const short8*)&KfH[((mtg + 0) * 2 + c) * 512 + lane * 8];
            short8 a0l = *(const short8*)&KfL[((mtg + 0) * 2 + c) * 512 + lane * 8];
            short8 a1h = *(const short8*)&KfH[((mtg + 1) * 2 + c) * 512 + lane * 8];
            short8 a1l = *(const short8*)&KfL[((mtg + 1) * 2 + c) * 512 + lane * 8];
            st0 = MFMA(a0h, qh[c], st0);
            st0 = MFMA(a0h, ql[c], st0);
            st0 = MFMA(a0l, qh[c], st0);
            st1 = MFMA(a1h, qh[c], st1);
            st1 = MFMA(a1h, ql[c], st1);
            st1 = MFMA(a1l, qh[c], st1);
        }

        // ---------------- online softmax (per query = per lane-column) ----------------
        f32x4 mk0 = *(const f32x4*)&MKs[kb + quad * 4];
        f32x4 mk1 = *(const f32x4*)&MKs[kb + 16 + quad * 4];
        float s0[4], s1[4];
#pragma unroll
        for (int r = 0; r < 4; r++) {
            s0[r] = st0[r] + (NEGC - apen * mk0[r]);
            s1[r] = st1[r] + (NEGC - apen * mk1[r]);
        }
        float cm = s0[0];
#pragma unroll
        for (int r = 1; r < 4; r++) cm = fmaxf(cm, s0[r]);
#pragma unroll
        for (int r = 0; r < 4; r++) cm = fmaxf(cm, s1[r]);
        cm = fmaxf(cm, __shfl_xor(cm, 16));
        cm = fmaxf(cm, __shfl_xor(cm, 32));
        float nm    = fmaxf(m, cm);
        float alpha = __expf(m - nm);
        m = nm;

        float p0[4], p1[4], cs = 0.0f;
#pragma unroll
        for (int r = 0; r < 4; r++) { p0[r] = __expf(s0[r] - nm); cs += p0[r]; }
#pragma unroll
        for (int r = 0; r < 4; r++) { p1[r] = __expf(s1[r] - nm); cs += p1[r]; }
        cs += __shfl_xor(cs, 16);
        cs += __shfl_xor(cs, 32);
        l   = l * alpha + cs;
        ot0 *= alpha; ot1 *= alpha; ot2 *= alpha; ot3 *= alpha;

        // ---------------- P -> bf16 -> per-wave LDS -> B-fragment ----------------
        uint2 pw0, pw1;
        pw0.x = (uint)f2bf(p0[0]) | ((uint)f2bf(p0[1]) << 16);
        pw0.y = (uint)f2bf(p0[2]) | ((uint)f2bf(p0[3]) << 16);
        pw1.x = (uint)f2bf(p1[0]) | ((uint)f2bf(p1[1]) << 16);
        pw1.y = (uint)f2bf(p1[2]) | ((uint)f2bf(p1[3]) << 16);
        int pidx0 = ((0 * 2 + (quad >> 1)) * 16 + lq) * 8 + (quad & 1) * 4;
        int pidx1 = ((1 * 2 + (quad >> 1)) * 16 + lq) * 8 + (quad & 1) * 4;
        *(uint2*)&Pw[pidx0] = pw0;
        *(uint2*)&Pw[pidx1] = pw1;
        short8 pfr = *(const short8*)&Pw[lane * 8];

        short8 v0 = *(const short8*)&Vf[(half * 4 + 0) * 512 + lane * 8];
        short8 v1 = *(const short8*)&Vf[(half * 4 + 1) * 512 + lane * 8];
        short8 v2 = *(const short8*)&Vf[(half * 4 + 2) * 512 + lane * 8];
        short8 v3 = *(const short8*)&Vf[(half * 4 + 3) * 512 + lane * 8];
        ot0 = MFMA(v0, pfr, ot0);
        ot1 = MFMA(v1, pfr, ot1);
        ot2 = MFMA(v2, pfr, ot2);
        ot3 = MFMA(v3, pfr, ot3);

        __syncthreads();
    }

    // ---------------- split-K merge (wave pair w, w+4) + store ----------------
    if (half == 1) {
        float* sc = &Msc[qg][lane * 20];
        *(f32x4*)&sc[0]  = ot0;
        *(f32x4*)&sc[4]  = ot1;
        *(f32x4*)&sc[8]  = ot2;
        *(f32x4*)&sc[12] = ot3;
        sc[16] = m;
        sc[17] = l;
    }
    __syncthreads();
    if (half == 0) {
        const float* sc = &Msc[qg][lane * 20];
        f32x4 ob0 = *(const f32x4*)&sc[0];
        f32x4 ob1 = *(const f32x4*)&sc[4];
        f32x4 ob2 = *(const f32x4*)&sc[8];
        f32x4 ob3 = *(const f32x4*)&sc[12];
        float mb = sc[16], lb = sc[17];

        float nm = fmaxf(m, mb);
        float fa = __expf(m - nm);
        float fb = __expf(mb - nm);
        float lt = l * fa + lb * fb;
        float inv = 1.0f / lt;

        float* Orow = O + ((size_t)b * SEQ + q) * DIM;
        f32x4 r0 = (ot0 * fa + ob0 * fb) * inv;
        f32x4 r1 = (ot1 * fa + ob1 * fb) * inv;
        f32x4 r2 = (ot2 * fa + ob2 * fb) * inv;
        f32x4 r3 = (ot3 * fa + ob3 * fb) * inv;
        *(f32x4*)(Orow + 0  + quad * 4) = r0;
        *(f32x4*)(Orow + 16 + quad * 4) = r1;
        *(f32x4*)(Orow + 32 + quad * 4) = r2;
        *(f32x4*)(Orow + 48 + quad * 4) = r3;
    }
}

extern "C" void kernel_launch(void* const* d_in, const int* in_sizes, int n_in,
                              void* d_out, int out_size, void* d_ws, size_t ws_size,
                              hipStream_t stream) {
    const float* Q  = (const float*)d_in[0];
    const float* K  = (const float*)d_in[1];
    const float* V  = (const float*)d_in[2];
    const float* MQ = (const float*)d_in[3];
    const float* MK = (const float*)d_in[4];
    const float* MV = (const float*)d_in[5];
    float* O = (float*)d_out;

    dim3 grid(BATCH * (SEQ / 64));
    dim3 block(512);
    attn_mfma<<<grid, block, 0, stream>>>(Q, K, V, MQ, MK, MV, O);
}

// Round 3
// 119.080 us; speedup vs baseline: 4.0371x; 1.1455x over previous
//
#include <hip/hip_runtime.h>
#include <math.h>

#define BATCH 8
#define SEQ   2048
#define DIM   64
#define NEGC  (-1e9f)

typedef short short8 __attribute__((ext_vector_type(8)));
typedef float f32x4  __attribute__((ext_vector_type(4)));

#define MFMA(a, b, c) __builtin_amdgcn_mfma_f32_16x16x32_bf16((a), (b), (c), 0, 0, 0)

__device__ __forceinline__ ushort f2bf(float x) {   // fp32 -> bf16 bits, RNE
    uint u = __float_as_uint(x);
    uint r = (u + 0x7fffu + ((u >> 16) & 1u)) >> 16;
    return (ushort)r;
}
__device__ __forceinline__ float bf2f(ushort h) {
    return __uint_as_float(((uint)h) << 16);
}

// ---------------------------------------------------------------------------
// ws layout: per (b, tile) a contiguous 24576 B image == LDS staging image:
//   [KfH 4096 ushort][KfL 4096 ushort][Vf 4096 ushort]
// KfH/KfL row r (8 ushorts): r = (mt*2+c)*64 + qd*16 + mm,
//   key = tile*64 + mt*16 + mm, d = c*32 + qd*8 + j   (j=0..7)
// Vf row r: r = (kg5*4+dg)*64 + kq*16 + dm,
//   key = tile*64 + kg5*32 + kq*8 + j, d = dg*16 + dm (j=0..7), V pre-masked.
// ---------------------------------------------------------------------------
__global__ __launch_bounds__(256)
void prep_kv(const float* __restrict__ K, const float* __restrict__ V,
             const float* __restrict__ MV, ushort* __restrict__ ws) {
    const int gid = blockIdx.x * 256 + threadIdx.x;   // 262144 total
    const int isV = gid >> 17;
    const int id  = gid & 131071;
    const int b   = id >> 14;          // 16384 rows per batch per half
    const int rt  = id & 16383;
    const int t   = rt >> 9;           // tile
    const int r   = rt & 511;          // row within tile image
    ushort* base = ws + (size_t)(b * 32 + t) * 12288;

    if (!isV) {
        const int mtc = r >> 6, qd = (r >> 4) & 3, mm = r & 15;
        const int mt = mtc >> 1, c = mtc & 1;
        const int key = t * 64 + mt * 16 + mm;
        const int d0  = c * 32 + qd * 8;
        const float* src = K + ((size_t)b * SEQ + key) * DIM + d0;
        float4 x0 = *(const float4*)src;
        float4 x1 = *(const float4*)(src + 4);
        float xs[8] = {x0.x, x0.y, x0.z, x0.w, x1.x, x1.y, x1.z, x1.w};
        short8 hv, lv;
#pragma unroll
        for (int j = 0; j < 8; j++) {
            ushort h = f2bf(xs[j]);
            hv[j] = (short)h;
            lv[j] = (short)f2bf(xs[j] - bf2f(h));
        }
        *(short8*)(base + r * 8)        = hv;
        *(short8*)(base + 4096 + r * 8) = lv;
    } else {
        const int kg5 = r >> 8, dg = (r >> 6) & 3, kq = (r >> 4) & 3, dm = r & 15;
        const int d  = dg * 16 + dm;
        const int k0 = t * 64 + kg5 * 32 + kq * 8;
        short8 ov;
#pragma unroll
        for (int j = 0; j < 8; j++) {
            const int key = k0 + j;
            float v = V[((size_t)b * SEQ + key) * DIM + d] * MV[(size_t)b * SEQ + key];
            ov[j] = (short)f2bf(v);
        }
        *(short8*)(base + 8192 + r * 8) = ov;
    }
}

// ---------------------------------------------------------------------------
// Main: 32 queries/block (grid 512 -> 2 blocks/CU), 256 thr = 4 waves.
// Wave w: qg = w&1 (16 queries), half = w>>1 (32 of the 64 staged keys).
// Sᵀ = K·Qᵀ hi/lo (3 MFMAs per 16k x 32d chunk), Oᵀ = Vᵀ·Pᵀ.
// ---------------------------------------------------------------------------
__global__ __launch_bounds__(256, 2)
void attn_main(const float* __restrict__ Q, const float* __restrict__ MQ,
               const float* __restrict__ MK, const ushort* __restrict__ ws,
               float* __restrict__ O) {
    __shared__ __align__(16) ushort Stage[12288];   // KfH | KfL | Vf
    __shared__ __align__(16) ushort Pf[4][512];
    __shared__ __align__(16) float  Msc[2][1280];

    const ushort* KfH = Stage;
    const ushort* KfL = Stage + 4096;
    const ushort* Vf  = Stage + 8192;

    const int t    = threadIdx.x;
    const int w    = t >> 6;
    const int lane = t & 63;
    const int quad = lane >> 4;
    const int lq   = lane & 15;
    const int qg   = w & 1;
    const int half = w >> 1;

    const int b  = blockIdx.x >> 6;
    const int q0 = (blockIdx.x & 63) * 32;
    const int q  = q0 + qg * 16 + lq;

    const float*  MKb = MK + (size_t)b * SEQ;
    const ushort* wsb = ws + (size_t)b * 32 * 12288;

    // Q fragments (B-operand layout), hi/lo, pre-scaled by 1/sqrt(D)
    short8 qh[2], ql[2];
    {
        const float* Qr = Q + ((size_t)b * SEQ + q) * DIM;
#pragma unroll
        for (int c = 0; c < 2; c++) {
            float4 x0 = *(const float4*)(Qr + c * 32 + quad * 8);
            float4 x1 = *(const float4*)(Qr + c * 32 + quad * 8 + 4);
            float xs[8] = {x0.x, x0.y, x0.z, x0.w, x1.x, x1.y, x1.z, x1.w};
#pragma unroll
            for (int j = 0; j < 8; j++) {
                float v   = xs[j] * 0.125f;
                ushort hi = f2bf(v);
                ql[c][j]  = (short)f2bf(v - bf2f(hi));
                qh[c][j]  = (short)hi;
            }
        }
    }
    const float mq   = MQ[(size_t)b * SEQ + q];
    const float apen = NEGC * mq;

    float m = -1e30f, l = 0.0f;
    f32x4 ot0 = {0,0,0,0}, ot1 = {0,0,0,0}, ot2 = {0,0,0,0}, ot3 = {0,0,0,0};

    ushort* Pw   = Pf[w];
    const int kb = half * 32;

#pragma unroll 1
    for (int tile = 0; tile < 32; tile++) {
        const ushort* src = wsb + (size_t)tile * 12288;
        // ---- stage 24 KB via global_load_lds (uniform base + lane*16) ----
#pragma unroll
        for (int u = 0; u < 6; u++) {
            const int off = (w * 64 + u * 256) * 8;     // ushort units
            __builtin_amdgcn_global_load_lds(
                (const __attribute__((address_space(1))) void*)(src + off + lane * 8),
                (__attribute__((address_space(3))) void*)(Stage + off),
                16, 0, 0);
        }
        __syncthreads();

        // ---- QK^T (this wave's 32 keys), hi/lo 3-MFMA ----
        f32x4 st0 = {0,0,0,0}, st1 = {0,0,0,0};
        const int mtg = half * 2;
#pragma unroll
        for (int c = 0; c < 2; c++) {
            short8 a0h = *(const short8*)&KfH[((mtg + 0) * 2 + c) * 512 + lane * 8];
            short8 a0l = *(const short8*)&KfL[((mtg + 0) * 2 + c) * 512 + lane * 8];
            short8 a1h = *(const short8*)&KfH[((mtg + 1) * 2 + c) * 512 + lane * 8];
            short8 a1l = *(const short8*)&KfL[((mtg + 1) * 2 + c) * 512 + lane * 8];
            st0 = MFMA(a0h, qh[c], st0);
            st0 = MFMA(a0h, ql[c], st0);
            st0 = MFMA(a0l, qh[c], st0);
            st1 = MFMA(a1h, qh[c], st1);
            st1 = MFMA(a1h, ql[c], st1);
            st1 = MFMA(a1l, qh[c], st1);
        }

        // ---- online softmax (per query = per lane-column) ----
        const float* mkp = MKb + tile * 64 + kb + quad * 4;
        float4 mk0 = *(const float4*)mkp;
        float4 mk1 = *(const float4*)(mkp + 16);
        float mks0[4] = {mk0.x, mk0.y, mk0.z, mk0.w};
        float mks1[4] = {mk1.x, mk1.y, mk1.z, mk1.w};
        float s0[4], s1[4];
#pragma unroll
        for (int r = 0; r < 4; r++) {
            s0[r] = st0[r] + (NEGC - apen * mks0[r]);
            s1[r] = st1[r] + (NEGC - apen * mks1[r]);
        }
        float cm = s0[0];
#pragma unroll
        for (int r = 1; r < 4; r++) cm = fmaxf(cm, s0[r]);
#pragma unroll
        for (int r = 0; r < 4; r++) cm = fmaxf(cm, s1[r]);
        cm = fmaxf(cm, __shfl_xor(cm, 16));
        cm = fmaxf(cm, __shfl_xor(cm, 32));
        float nm    = fmaxf(m, cm);
        float alpha = __expf(m - nm);
        m = nm;

        float p0[4], p1[4], cs = 0.0f;
#pragma unroll
        for (int r = 0; r < 4; r++) { p0[r] = __expf(s0[r] - nm); cs += p0[r]; }
#pragma unroll
        for (int r = 0; r < 4; r++) { p1[r] = __expf(s1[r] - nm); cs += p1[r]; }
        cs += __shfl_xor(cs, 16);
        cs += __shfl_xor(cs, 32);
        l   = l * alpha + cs;
        ot0 *= alpha; ot1 *= alpha; ot2 *= alpha; ot3 *= alpha;

        // ---- P -> bf16 -> per-wave LDS roundtrip -> B-fragment ----
        uint2 pw0, pw1;
        pw0.x = (uint)f2bf(p0[0]) | ((uint)f2bf(p0[1]) << 16);
        pw0.y = (uint)f2bf(p0[2]) | ((uint)f2bf(p0[3]) << 16);
        pw1.x = (uint)f2bf(p1[0]) | ((uint)f2bf(p1[1]) << 16);
        pw1.y = (uint)f2bf(p1[2]) | ((uint)f2bf(p1[3]) << 16);
        int pidx0 = ((0 * 2 + (quad >> 1)) * 16 + lq) * 8 + (quad & 1) * 4;
        int pidx1 = ((1 * 2 + (quad >> 1)) * 16 + lq) * 8 + (quad & 1) * 4;
        *(uint2*)&Pw[pidx0] = pw0;
        *(uint2*)&Pw[pidx1] = pw1;
        short8 pfr = *(const short8*)&Pw[lane * 8];

        // ---- PV (this wave's 32 keys x all 64 dims) ----
        short8 v0 = *(const short8*)&Vf[(half * 4 + 0) * 512 + lane * 8];
        short8 v1 = *(const short8*)&Vf[(half * 4 + 1) * 512 + lane * 8];
        short8 v2 = *(const short8*)&Vf[(half * 4 + 2) * 512 + lane * 8];
        short8 v3 = *(const short8*)&Vf[(half * 4 + 3) * 512 + lane * 8];
        ot0 = MFMA(v0, pfr, ot0);
        ot1 = MFMA(v1, pfr, ot1);
        ot2 = MFMA(v2, pfr, ot2);
        ot3 = MFMA(v3, pfr, ot3);

        __syncthreads();
    }

    // ---- 2-way split-K merge + store ----
    if (half == 1) {
        float* sc = &Msc[qg][lane * 20];
        *(f32x4*)&sc[0]  = ot0;
        *(f32x4*)&sc[4]  = ot1;
        *(f32x4*)&sc[8]  = ot2;
        *(f32x4*)&sc[12] = ot3;
        sc[16] = m;
        sc[17] = l;
    }
    __syncthreads();
    if (half == 0) {
        const float* sc = &Msc[qg][lane * 20];
        f32x4 ob0 = *(const f32x4*)&sc[0];
        f32x4 ob1 = *(const f32x4*)&sc[4];
        f32x4 ob2 = *(const f32x4*)&sc[8];
        f32x4 ob3 = *(const f32x4*)&sc[12];
        float mb = sc[16], lb = sc[17];

        float nm  = fmaxf(m, mb);
        float fa  = __expf(m - nm);
        float fb  = __expf(mb - nm);
        float inv = 1.0f / (l * fa + lb * fb);

        float* Orow = O + ((size_t)b * SEQ + q) * DIM;
        *(f32x4*)(Orow + 0  + quad * 4) = (ot0 * fa + ob0 * fb) * inv;
        *(f32x4*)(Orow + 16 + quad * 4) = (ot1 * fa + ob1 * fb) * inv;
        *(f32x4*)(Orow + 32 + quad * 4) = (ot2 * fa + ob2 * fb) * inv;
        *(f32x4*)(Orow + 48 + quad * 4) = (ot3 * fa + ob3 * fb) * inv;
    }
}

extern "C" void kernel_launch(void* const* d_in, const int* in_sizes, int n_in,
                              void* d_out, int out_size, void* d_ws, size_t ws_size,
                              hipStream_t stream) {
    const float* Q  = (const float*)d_in[0];
    const float* K  = (const float*)d_in[1];
    const float* V  = (const float*)d_in[2];
    const float* MQ = (const float*)d_in[3];
    const float* MK = (const float*)d_in[4];
    const float* MV = (const float*)d_in[5];
    float* O   = (float*)d_out;
    ushort* ws = (ushort*)d_ws;

    prep_kv<<<dim3(1024), dim3(256), 0, stream>>>(K, V, MV, ws);
    attn_main<<<dim3(BATCH * (SEQ / 32)), dim3(256), 0, stream>>>(Q, MQ, MK, ws, O);
}

// Round 4
// 108.466 us; speedup vs baseline: 4.4321x; 1.0979x over previous
//
#include <hip/hip_runtime.h>
#include <hip/hip_bf16.h>
#include <math.h>

#define BATCH 8
#define SEQ   2048
#define DIM   64
#define NEGC  (-1e9f)

typedef short short8 __attribute__((ext_vector_type(8)));
typedef float f32x4  __attribute__((ext_vector_type(4)));

#define MFMA(a, b, c) __builtin_amdgcn_mfma_f32_16x16x32_bf16((a), (b), (c), 0, 0, 0)

__device__ __forceinline__ ushort f2bf(float x) {   // fp32 -> bf16 bits, RNE
    uint u = __float_as_uint(x);
    uint r = (u + 0x7fffu + ((u >> 16) & 1u)) >> 16;
    return (ushort)r;
}
__device__ __forceinline__ float bf2f(ushort h) {
    return __uint_as_float(((uint)h) << 16);
}

// ---------------------------------------------------------------------------
// ws layout: per (b, tile) 16384 B image == LDS staging image:
//   [Kh 4096 ushort][Vf 4096 ushort]
// Kh row r: r = (mt*2+c)*64 + qd*16 + mm -> K[key=mt*16+mm][d=c*32+qd*8+j]
// Vf row r: r = (kg5*4+dg)*64 + kq*16+dm -> V[key=kg5*32+kq*8+j][d=dg*16+dm]
// (V pre-masked by mask_v). Transform goes via a padded raw LDS tile so both
// the global read (float4, coalesced) and the ws write (16B, coalesced) are
// clean; LDS scatter conflicts are absorbed there (prep is ~5 us total).
// ---------------------------------------------------------------------------
__global__ __launch_bounds__(256)
void prep_kv(const float* __restrict__ K, const float* __restrict__ V,
             const float* __restrict__ MV, ushort* __restrict__ ws) {
    __shared__ float raw[64 * 68];   // stride 68 floats: breaks pow-2 banks, keeps 16B align
    const int t    = threadIdx.x;
    const int b    = blockIdx.x >> 5;
    const int tile = blockIdx.x & 31;
    const float* Kb  = K  + ((size_t)b * SEQ + tile * 64) * DIM;
    const float* Vb  = V  + ((size_t)b * SEQ + tile * 64) * DIM;
    const float* MVb = MV + (size_t)b * SEQ + tile * 64;
    ushort* wsI = ws + (size_t)(b * 32 + tile) * 8192;

    // ---- K phase ----
#pragma unroll
    for (int u = 0; u < 4; u++) {
        int f = t + 256 * u, key = f >> 4, d4 = (f & 15) * 4;
        *(float4*)&raw[key * 68 + d4] = *(const float4*)(Kb + (size_t)f * 4);
    }
    __syncthreads();
#pragma unroll
    for (int u = 0; u < 2; u++) {
        int r = t + 256 * u;
        int mtc = r >> 6, qd = (r >> 4) & 3, mm = r & 15;
        int mt = mtc >> 1, c = mtc & 1;
        int key = mt * 16 + mm, d0 = c * 32 + qd * 8;
        float4 x0 = *(float4*)&raw[key * 68 + d0];
        float4 x1 = *(float4*)&raw[key * 68 + d0 + 4];
        float xs[8] = {x0.x, x0.y, x0.z, x0.w, x1.x, x1.y, x1.z, x1.w};
        short8 hv;
#pragma unroll
        for (int j = 0; j < 8; j++) hv[j] = (short)f2bf(xs[j]);
        *(short8*)(wsI + r * 8) = hv;
    }
    __syncthreads();

    // ---- V phase (mask_v folded in) ----
#pragma unroll
    for (int u = 0; u < 4; u++) {
        int f = t + 256 * u, key = f >> 4, d4 = (f & 15) * 4;
        float4 x = *(const float4*)(Vb + (size_t)f * 4);
        float mv = MVb[key];
        x.x *= mv; x.y *= mv; x.z *= mv; x.w *= mv;
        *(float4*)&raw[key * 68 + d4] = x;
    }
    __syncthreads();
#pragma unroll
    for (int u = 0; u < 2; u++) {
        int r = t + 256 * u;
        int kg5 = r >> 8, dg = (r >> 6) & 3, kq = (r >> 4) & 3, dm = r & 15;
        int d = dg * 16 + dm, k0 = kg5 * 32 + kq * 8;
        short8 ov;
#pragma unroll
        for (int j = 0; j < 8; j++) ov[j] = (short)f2bf(raw[(k0 + j) * 68 + d]);
        *(short8*)(wsI + 4096 + r * 8) = ov;
    }
}

// ---------------------------------------------------------------------------
// Main: 64 queries/block, 512 thr = 8 waves, grid 256 (1 block/CU).
// Wave w: qg = w&3 (16 queries), half = w>>2 (32 of the 64 staged keys).
// Double-buffered LDS staging: issue tile t+1 at top of tile t; single
// barrier per tile (its vmcnt(0) drain doubles as the staging fence, and
// the loads had a full compute phase in flight).
// ---------------------------------------------------------------------------
__global__ __launch_bounds__(512, 2)
void attn_main(const float* __restrict__ Q, const float* __restrict__ MQ,
               const float* __restrict__ MK, const ushort* __restrict__ ws,
               float* __restrict__ O) {
    __shared__ __align__(16) ushort Stage[2][8192];   // [Kh 4096 | Vf 4096] x2
    __shared__ __align__(16) ushort Pf[8][512];
    __shared__ __align__(16) float  Msc[4][1280];

    const int t    = threadIdx.x;
    const int w    = t >> 6;
    const int lane = t & 63;
    const int quad = lane >> 4;
    const int lq   = lane & 15;
    const int qg   = w & 3;
    const int half = w >> 2;

    const int b  = blockIdx.x >> 5;
    const int q0 = (blockIdx.x & 31) * 64;
    const int q  = q0 + qg * 16 + lq;

    const float*  MKb = MK + (size_t)b * SEQ;
    const ushort* wsb = ws + (size_t)b * 32 * 8192;

    // Q fragments (B-operand layout), hi/lo, pre-scaled by 1/sqrt(D)
    short8 qh[2], ql[2];
    {
        const float* Qr = Q + ((size_t)b * SEQ + q) * DIM;
#pragma unroll
        for (int c = 0; c < 2; c++) {
            float4 x0 = *(const float4*)(Qr + c * 32 + quad * 8);
            float4 x1 = *(const float4*)(Qr + c * 32 + quad * 8 + 4);
            float xs[8] = {x0.x, x0.y, x0.z, x0.w, x1.x, x1.y, x1.z, x1.w};
#pragma unroll
            for (int j = 0; j < 8; j++) {
                float v   = xs[j] * 0.125f;
                ushort hi = f2bf(v);
                ql[c][j]  = (short)f2bf(v - bf2f(hi));
                qh[c][j]  = (short)hi;
            }
        }
    }
    const float mq   = MQ[(size_t)b * SEQ + q];
    const float apen = NEGC * mq;

    float m = -1e30f, l = 0.0f;
    f32x4 ot0 = {0,0,0,0}, ot1 = {0,0,0,0}, ot2 = {0,0,0,0}, ot3 = {0,0,0,0};

    ushort* Pw   = Pf[w];
    const int kb = half * 32;

    // ---- stage tile 0 into buf 0 ----
#pragma unroll
    for (int u = 0; u < 2; u++) {
        const int off = u * 4096 + w * 512;        // ushort units, wave-uniform
        __builtin_amdgcn_global_load_lds(
            (const __attribute__((address_space(1))) void*)(wsb + off + lane * 8),
            (__attribute__((address_space(3))) void*)(&Stage[0][0] + off),
            16, 0, 0);
    }
    __syncthreads();

    // mask_k row for tile 0 (prefetched one tile ahead thereafter)
    f32x4 mkA = *(const f32x4*)(MKb + kb + quad * 4);
    f32x4 mkB = *(const f32x4*)(MKb + kb + 16 + quad * 4);

#pragma unroll 1
    for (int tile = 0; tile < 32; tile++) {
        const ushort* cur = &Stage[tile & 1][0];

        // ---- prefetch tile+1 into the other buffer (no wait here) ----
        if (tile + 1 < 32) {
            const ushort* src = wsb + (size_t)(tile + 1) * 8192;
            ushort* dst = &Stage[(tile + 1) & 1][0];
#pragma unroll
            for (int u = 0; u < 2; u++) {
                const int off = u * 4096 + w * 512;
                __builtin_amdgcn_global_load_lds(
                    (const __attribute__((address_space(1))) void*)(src + off + lane * 8),
                    (__attribute__((address_space(3))) void*)(dst + off),
                    16, 0, 0);
            }
        }
        // prefetch next tile's mask_k row into registers
        f32x4 nA = mkA, nB = mkB;
        if (tile + 1 < 32) {
            const float* mkp = MKb + (tile + 1) * 64 + kb + quad * 4;
            nA = *(const f32x4*)mkp;
            nB = *(const f32x4*)(mkp + 16);
        }

        // ---- QK^T: 16q (qg) x 32k (half) x 64d, K-hi only, Q hi/lo ----
        f32x4 st0 = {0,0,0,0}, st1 = {0,0,0,0};
        const int mtg = half * 2;
#pragma unroll
        for (int c = 0; c < 2; c++) {
            short8 a0 = *(const short8*)&cur[((mtg + 0) * 2 + c) * 512 + lane * 8];
            short8 a1 = *(const short8*)&cur[((mtg + 1) * 2 + c) * 512 + lane * 8];
            st0 = MFMA(a0, qh[c], st0);
            st0 = MFMA(a0, ql[c], st0);
            st1 = MFMA(a1, qh[c], st1);
            st1 = MFMA(a1, ql[c], st1);
        }

        // ---- online softmax (per query = per lane-column) ----
        float s0[4], s1[4];
#pragma unroll
        for (int r = 0; r < 4; r++) {
            s0[r] = st0[r] + (NEGC - apen * mkA[r]);
            s1[r] = st1[r] + (NEGC - apen * mkB[r]);
        }
        float cm = s0[0];
#pragma unroll
        for (int r = 1; r < 4; r++) cm = fmaxf(cm, s0[r]);
#pragma unroll
        for (int r = 0; r < 4; r++) cm = fmaxf(cm, s1[r]);
        cm = fmaxf(cm, __shfl_xor(cm, 16));
        cm = fmaxf(cm, __shfl_xor(cm, 32));
        float nm    = fmaxf(m, cm);
        float alpha = __expf(m - nm);
        m = nm;

        float p0[4], p1[4], cs = 0.0f;
#pragma unroll
        for (int r = 0; r < 4; r++) { p0[r] = __expf(s0[r] - nm); cs += p0[r]; }
#pragma unroll
        for (int r = 0; r < 4; r++) { p1[r] = __expf(s1[r] - nm); cs += p1[r]; }
        cs += __shfl_xor(cs, 16);
        cs += __shfl_xor(cs, 32);
        l   = l * alpha + cs;
        ot0 *= alpha; ot1 *= alpha; ot2 *= alpha; ot3 *= alpha;

        // ---- P -> bf16 (packed cvt) -> per-wave LDS roundtrip -> B-frag ----
        __hip_bfloat162 c0 = __float22bfloat162_rn(make_float2(p0[0], p0[1]));
        __hip_bfloat162 c1 = __float22bfloat162_rn(make_float2(p0[2], p0[3]));
        __hip_bfloat162 c2 = __float22bfloat162_rn(make_float2(p1[0], p1[1]));
        __hip_bfloat162 c3 = __float22bfloat162_rn(make_float2(p1[2], p1[3]));
        uint2 pw0, pw1;
        __builtin_memcpy(&pw0.x, &c0, 4);
        __builtin_memcpy(&pw0.y, &c1, 4);
        __builtin_memcpy(&pw1.x, &c2, 4);
        __builtin_memcpy(&pw1.y, &c3, 4);
        int pidx0 = ((0 * 2 + (quad >> 1)) * 16 + lq) * 8 + (quad & 1) * 4;
        int pidx1 = ((1 * 2 + (quad >> 1)) * 16 + lq) * 8 + (quad & 1) * 4;
        *(uint2*)&Pw[pidx0] = pw0;
        *(uint2*)&Pw[pidx1] = pw1;
        short8 pfr = *(const short8*)&Pw[lane * 8];

        // ---- PV: this wave's 32 keys x all 64 dims ----
        const ushort* VfC = cur + 4096;
        short8 v0 = *(const short8*)&VfC[(half * 4 + 0) * 512 + lane * 8];
        short8 v1 = *(const short8*)&VfC[(half * 4 + 1) * 512 + lane * 8];
        short8 v2 = *(const short8*)&VfC[(half * 4 + 2) * 512 + lane * 8];
        short8 v3 = *(const short8*)&VfC[(half * 4 + 3) * 512 + lane * 8];
        ot0 = MFMA(v0, pfr, ot0);
        ot1 = MFMA(v1, pfr, ot1);
        ot2 = MFMA(v2, pfr, ot2);
        ot3 = MFMA(v3, pfr, ot3);

        mkA = nA; mkB = nB;
        __syncthreads();   // drains this tile's prefetch; protects both buffers
    }

    // ---- 2-way split-K merge + store ----
    if (half == 1) {
        float* sc = &Msc[qg][lane * 20];
        *(f32x4*)&sc[0]  = ot0;
        *(f32x4*)&sc[4]  = ot1;
        *(f32x4*)&sc[8]  = ot2;
        *(f32x4*)&sc[12] = ot3;
        sc[16] = m;
        sc[17] = l;
    }
    __syncthreads();
    if (half == 0) {
        const float* sc = &Msc[qg][lane * 20];
        f32x4 ob0 = *(const f32x4*)&sc[0];
        f32x4 ob1 = *(const f32x4*)&sc[4];
        f32x4 ob2 = *(const f32x4*)&sc[8];
        f32x4 ob3 = *(const f32x4*)&sc[12];
        float mb = sc[16], lb = sc[17];

        float nm  = fmaxf(m, mb);
        float fa  = __expf(m - nm);
        float fb  = __expf(mb - nm);
        float inv = 1.0f / (l * fa + lb * fb);

        float* Orow = O + ((size_t)b * SEQ + q) * DIM;
        *(f32x4*)(Orow + 0  + quad * 4) = (ot0 * fa + ob0 * fb) * inv;
        *(f32x4*)(Orow + 16 + quad * 4) = (ot1 * fa + ob1 * fb) * inv;
        *(f32x4*)(Orow + 32 + quad * 4) = (ot2 * fa + ob2 * fb) * inv;
        *(f32x4*)(Orow + 48 + quad * 4) = (ot3 * fa + ob3 * fb) * inv;
    }
}

extern "C" void kernel_launch(void* const* d_in, const int* in_sizes, int n_in,
                              void* d_out, int out_size, void* d_ws, size_t ws_size,
                              hipStream_t stream) {
    const float* Q  = (const float*)d_in[0];
    const float* K  = (const float*)d_in[1];
    const float* V  = (const float*)d_in[2];
    const float* MQ = (const float*)d_in[3];
    const float* MK = (const float*)d_in[4];
    const float* MV = (const float*)d_in[5];
    float* O   = (float*)d_out;
    ushort* ws = (ushort*)d_ws;

    prep_kv<<<dim3(256), dim3(256), 0, stream>>>(K, V, MV, ws);
    attn_main<<<dim3(BATCH * (SEQ / 64)), dim3(512), 0, stream>>>(Q, MQ, MK, ws, O);
}

// Round 5
// 101.740 us; speedup vs baseline: 4.7251x; 1.0661x over previous
//
#include <hip/hip_runtime.h>
#include <hip/hip_bf16.h>
#include <math.h>

#define BATCH 8
#define SEQ   2048
#define DIM   64
#define NEGC  (-1e9f)

typedef short short8  __attribute__((ext_vector_type(8)));
typedef float f32x4   __attribute__((ext_vector_type(4)));
typedef float f32x16  __attribute__((ext_vector_type(16)));

#define MFMA32(a, b, c) __builtin_amdgcn_mfma_f32_32x32x16_bf16((a), (b), (c), 0, 0, 0)

__device__ __forceinline__ ushort f2bf(float x) {   // fp32 -> bf16 bits, RNE
    uint u = __float_as_uint(x);
    uint r = (u + 0x7fffu + ((u >> 16) & 1u)) >> 16;
    return (ushort)r;
}
__device__ __forceinline__ float bf2f(ushort h) {
    return __uint_as_float(((uint)h) << 16);
}

// ---------------------------------------------------------------------------
// ws layout:
//   [0, 4MB):   KV frag images, per (b,tile) 16384 B = [Kh 8KB][Vf 8KB]
//     Kh row r (8 bf16, 16B): r=(mt*4+kc)*64+L ->
//        K[key=mt*32+(L&31)][d=kc*16+(L>>5)*8+j]     (A-frag for 32x32x16)
//     Vf row r: r=(dt*4+kc)*64+L ->
//        V[key=kc*16+(L>>5)*8+j][d=dt*32+(L&31)]     (A-frag, V pre-masked)
//   [4MB,12MB):  PO partials [s][b][qt][q 64][d 64] f32
//   [12MB,..):   ML partials [s][b][qt][q 64] float2 {m,l}
// ---------------------------------------------------------------------------
__global__ __launch_bounds__(256)
void prep_kv(const float* __restrict__ K, const float* __restrict__ V,
             const float* __restrict__ MV, ushort* __restrict__ ws) {
    __shared__ float raw[64 * 68];
    const int t    = threadIdx.x;
    const int b    = blockIdx.x >> 5;
    const int tile = blockIdx.x & 31;
    const float* Kb  = K  + ((size_t)b * SEQ + tile * 64) * DIM;
    const float* Vb  = V  + ((size_t)b * SEQ + tile * 64) * DIM;
    const float* MVb = MV + (size_t)b * SEQ + tile * 64;
    ushort* wsI = ws + (size_t)(b * 32 + tile) * 8192;

    // ---- K ----
#pragma unroll
    for (int u = 0; u < 4; u++) {
        int f = t + 256 * u, key = f >> 4, d4 = (f & 15) * 4;
        *(float4*)&raw[key * 68 + d4] = *(const float4*)(Kb + (size_t)f * 4);
    }
    __syncthreads();
#pragma unroll
    for (int u = 0; u < 2; u++) {
        int r = t + 256 * u;
        int mt = r >> 8, kc = (r >> 6) & 3, L = r & 63;
        int key = mt * 32 + (L & 31), d0 = kc * 16 + (L >> 5) * 8;
        float4 x0 = *(float4*)&raw[key * 68 + d0];
        float4 x1 = *(float4*)&raw[key * 68 + d0 + 4];
        float xs[8] = {x0.x, x0.y, x0.z, x0.w, x1.x, x1.y, x1.z, x1.w};
        short8 hv;
#pragma unroll
        for (int j = 0; j < 8; j++) hv[j] = (short)f2bf(xs[j]);
        *(short8*)(wsI + r * 8) = hv;
    }
    __syncthreads();

    // ---- V (mask_v folded) ----
#pragma unroll
    for (int u = 0; u < 4; u++) {
        int f = t + 256 * u, key = f >> 4, d4 = (f & 15) * 4;
        float4 x = *(const float4*)(Vb + (size_t)f * 4);
        float mv = MVb[key];
        x.x *= mv; x.y *= mv; x.z *= mv; x.w *= mv;
        *(float4*)&raw[key * 68 + d4] = x;
    }
    __syncthreads();
#pragma unroll
    for (int u = 0; u < 2; u++) {
        int r = t + 256 * u;
        int dt = r >> 8, kc = (r >> 6) & 3, L = r & 63;
        int d = dt * 32 + (L & 31), k0 = kc * 16 + (L >> 5) * 8;
        short8 ov;
#pragma unroll
        for (int j = 0; j < 8; j++) ov[j] = (short)f2bf(raw[(k0 + j) * 68 + d]);
        *(short8*)(wsI + 4096 + r * 8) = ov;
    }
}

// ---------------------------------------------------------------------------
// Main: 256 thr = 4 waves (2 qg x 2 kh), 64 q/block, 2-way split-K across
// blocks (16 k-tiles each). Grid 512 -> 2 blocks/CU. 32x32x16 MFMA.
// Sᵀ = K·Qᵀ (Q hi/lo), P exchanged in-register (shfl_xor 32), Oᵀ = Vᵀ·Pᵀ.
// 32x32 C/D: col=lane&31, row=(reg&3)+8*(reg>>2)+4*(lane>>5).
// A/B: X[i=lane&31][k=(lane>>5)*8+j].
// ---------------------------------------------------------------------------
__global__ __launch_bounds__(256, 2)
void attn_main(const float* __restrict__ Q, const float* __restrict__ MQ,
               const float* __restrict__ MK, const ushort* __restrict__ ws,
               float* __restrict__ PO, float* __restrict__ ML) {
    __shared__ __align__(16) ushort Stage[2][8192];   // [Kh 4096 us | Vf 4096 us] x2
    __shared__ __align__(16) float  Msc[2][64 * 34];

    const int t    = threadIdx.x;
    const int w    = t >> 6;
    const int lane = t & 63;
    const int h    = lane >> 5;
    const int lm   = lane & 31;
    const int qg   = w & 1;
    const int kh   = w >> 1;

    const int s  = blockIdx.x & 1;          // k-split
    const int qb = blockIdx.x >> 1;
    const int b  = qb >> 5;
    const int qt = qb & 31;
    const int q  = qt * 64 + qg * 32 + lm;

    const float*  MKb  = MK + (size_t)b * SEQ;
    const ushort* wsKV = ws + (size_t)b * 32 * 8192;

    // ---- Q fragments (B-operand), hi/lo, pre-scaled by 1/8 ----
    short8 qh[4], ql[4];
    {
        const float* Qr = Q + ((size_t)b * SEQ + q) * DIM;
#pragma unroll
        for (int kc = 0; kc < 4; kc++) {
            const float* p = Qr + kc * 16 + h * 8;
            float4 x0 = *(const float4*)p;
            float4 x1 = *(const float4*)(p + 4);
            float xs[8] = {x0.x, x0.y, x0.z, x0.w, x1.x, x1.y, x1.z, x1.w};
#pragma unroll
            for (int j = 0; j < 8; j++) {
                float v   = xs[j] * 0.125f;
                ushort hi = f2bf(v);
                ql[kc][j] = (short)f2bf(v - bf2f(hi));
                qh[kc][j] = (short)hi;
            }
        }
    }
    const float mq   = MQ[(size_t)b * SEQ + q];
    const float apen = NEGC * mq;

    float m = -1e30f, l = 0.0f;
    f32x16 ot0, ot1;
#pragma unroll
    for (int i = 0; i < 16; i++) { ot0[i] = 0.0f; ot1[i] = 0.0f; }

    // ---- stage first tile ----
    {
        const ushort* src = wsKV + (size_t)(s * 16) * 8192;
#pragma unroll
        for (int u = 0; u < 4; u++) {
            const int off = (u * 256 + w * 64 + lane) * 8;
            __builtin_amdgcn_global_load_lds(
                (const __attribute__((address_space(1))) void*)(src + off),
                (__attribute__((address_space(3))) void*)(&Stage[0][0] + off),
                16, 0, 0);
        }
    }
    __syncthreads();

    f32x4 mk[4];
#pragma unroll
    for (int v = 0; v < 4; v++)
        mk[v] = *(const f32x4*)(MKb + (s * 16) * 64 + kh * 32 + v * 8 + h * 4);

#pragma unroll 1
    for (int tt = 0; tt < 16; tt++) {
        const ushort* cur = &Stage[tt & 1][0];

        // ---- prefetch next tile (no wait) ----
        if (tt + 1 < 16) {
            const ushort* src = wsKV + (size_t)(s * 16 + tt + 1) * 8192;
            ushort* dst = &Stage[(tt + 1) & 1][0];
#pragma unroll
            for (int u = 0; u < 4; u++) {
                const int off = (u * 256 + w * 64 + lane) * 8;
                __builtin_amdgcn_global_load_lds(
                    (const __attribute__((address_space(1))) void*)(src + off),
                    (__attribute__((address_space(3))) void*)(dst + off),
                    16, 0, 0);
            }
        }
        f32x4 nmk[4];
#pragma unroll
        for (int v = 0; v < 4; v++) nmk[v] = mk[v];
        if (tt + 1 < 16) {
            const float* mkp = MKb + (s * 16 + tt + 1) * 64 + kh * 32 + h * 4;
#pragma unroll
            for (int v = 0; v < 4; v++) nmk[v] = *(const f32x4*)(mkp + v * 8);
        }

        // ---- QK^T: 32q x 32k x 64d, K hi, Q hi/lo ----
        f32x16 st;
#pragma unroll
        for (int i = 0; i < 16; i++) st[i] = 0.0f;
#pragma unroll
        for (int kc = 0; kc < 4; kc++) {
            short8 a = *(const short8*)&cur[((kh * 4 + kc) * 64 + lane) * 8];
            st = MFMA32(a, qh[kc], st);
            st = MFMA32(a, ql[kc], st);
        }

        // ---- online softmax: lane holds 16 keys of its query column ----
        float sv[16];
#pragma unroll
        for (int v = 0; v < 4; v++)
#pragma unroll
            for (int c = 0; c < 4; c++)
                sv[v * 4 + c] = st[v * 4 + c] + (NEGC - apen * mk[v][c]);
        float cm = sv[0];
#pragma unroll
        for (int i = 1; i < 16; i++) cm = fmaxf(cm, sv[i]);
        cm = fmaxf(cm, __shfl_xor(cm, 32));
        float nm    = fmaxf(m, cm);
        float alpha = __expf(m - nm);
        m = nm;

        float p[16], cs = 0.0f;
#pragma unroll
        for (int i = 0; i < 16; i++) { p[i] = __expf(sv[i] - nm); cs += p[i]; }
        cs += __shfl_xor(cs, 32);
        l   = l * alpha + cs;
        ot0 *= alpha; ot1 *= alpha;

        // ---- P: C-layout -> B-frags via half-wave exchange ----
        uint g[4][2], x[4][2];
#pragma unroll
        for (int v = 0; v < 4; v++) {
            __hip_bfloat162 c0 = __float22bfloat162_rn(make_float2(p[v*4+0], p[v*4+1]));
            __hip_bfloat162 c1 = __float22bfloat162_rn(make_float2(p[v*4+2], p[v*4+3]));
            __builtin_memcpy(&g[v][0], &c0, 4);
            __builtin_memcpy(&g[v][1], &c1, 4);
            x[v][0] = (uint)__shfl_xor((int)g[v][0], 32);
            x[v][1] = (uint)__shfl_xor((int)g[v][1], 32);
        }
        uint pbw[2][4];
        pbw[0][0] = h ? x[1][0] : g[0][0];
        pbw[0][1] = h ? x[1][1] : g[0][1];
        pbw[0][2] = h ? g[1][0] : x[0][0];
        pbw[0][3] = h ? g[1][1] : x[0][1];
        pbw[1][0] = h ? x[3][0] : g[2][0];
        pbw[1][1] = h ? x[3][1] : g[2][1];
        pbw[1][2] = h ? g[3][0] : x[2][0];
        pbw[1][3] = h ? g[3][1] : x[2][1];

        // ---- PV: Oᵀ = Vᵀ·Pᵀ over this wave's 32 keys ----
#pragma unroll
        for (int c = 0; c < 2; c++) {
            short8 pb;
            __builtin_memcpy(&pb, &pbw[c][0], 16);
            short8 v0 = *(const short8*)&cur[4096 + ((0 * 4 + kh * 2 + c) * 64 + lane) * 8];
            short8 v1 = *(const short8*)&cur[4096 + ((1 * 4 + kh * 2 + c) * 64 + lane) * 8];
            ot0 = MFMA32(v0, pb, ot0);
            ot1 = MFMA32(v1, pb, ot1);
        }

#pragma unroll
        for (int v = 0; v < 4; v++) mk[v] = nmk[v];
        __syncthreads();
    }

    // ---- intra-block kh merge + partial store ----
    if (kh == 1) {
        float* sc = &Msc[qg][lane * 34];
#pragma unroll
        for (int i = 0; i < 16; i++) { sc[i] = ot0[i]; sc[16 + i] = ot1[i]; }
        sc[32] = m;
        sc[33] = l;
    }
    __syncthreads();
    if (kh == 0) {
        const float* sc = &Msc[qg][lane * 34];
        float mb = sc[32], lb = sc[33];
        float nm = fmaxf(m, mb);
        float fa = __expf(m - nm);
        float fb = __expf(mb - nm);
        float lt = l * fa + lb * fb;

        float* po = PO + (((size_t)(s * 8 + b) * 32 + qt) * 64 + qg * 32 + lm) * 64;
#pragma unroll
        for (int dt = 0; dt < 2; dt++) {
            const f32x16& o = dt ? ot1 : ot0;
#pragma unroll
            for (int rq = 0; rq < 4; rq++) {
                f32x4 r;
#pragma unroll
                for (int c = 0; c < 4; c++)
                    r[c] = o[rq * 4 + c] * fa + sc[dt * 16 + rq * 4 + c] * fb;
                *(f32x4*)(po + dt * 32 + rq * 8 + h * 4) = r;
            }
        }
        if (h == 0) {
            float2* ml2 = (float2*)ML;
            ml2[((size_t)(s * 8 + b) * 32 + qt) * 64 + qg * 32 + lm] =
                make_float2(nm, lt);
        }
    }
}

// ---------------------------------------------------------------------------
// Cross-block split-K merge: O = (O0*e^{m0-m} + O1*e^{m1-m}) / (l0*.. + l1*..)
// ---------------------------------------------------------------------------
__global__ __launch_bounds__(256)
void merge_o(const float* __restrict__ PO, const float* __restrict__ ML,
             float* __restrict__ O) {
    const int tid = blockIdx.x * 256 + threadIdx.x;
    const int qln = tid >> 4;          // 0..16383
    const int dq  = tid & 15;
    const int b   = qln >> 11;
    const int qr  = qln & 2047;
    const int qt  = qr >> 6;
    const int qq  = qr & 63;

    const float2* ml2 = (const float2*)ML;
    const size_t mlidx = ((size_t)b * 32 + qt) * 64 + qq;
    float2 A = ml2[mlidx];
    float2 Bv = ml2[(size_t)8 * 32 * 64 + mlidx];
    float mm = fmaxf(A.x, Bv.x);
    float fa = __expf(A.x - mm);
    float fb = __expf(Bv.x - mm);
    float inv = 1.0f / (A.y * fa + Bv.y * fb);

    const size_t o0 = (((size_t)b * 32 + qt) * 64 + qq) * 64 + dq * 4;
    f32x4 va = *(const f32x4*)(PO + o0);
    f32x4 vb = *(const f32x4*)(PO + (size_t)8 * 32 * 64 * 64 + o0);
    f32x4 r = (va * fa + vb * fb) * inv;
    *(f32x4*)(O + ((size_t)b * SEQ + qr) * DIM + dq * 4) = r;
}

extern "C" void kernel_launch(void* const* d_in, const int* in_sizes, int n_in,
                              void* d_out, int out_size, void* d_ws, size_t ws_size,
                              hipStream_t stream) {
    const float* Q  = (const float*)d_in[0];
    const float* K  = (const float*)d_in[1];
    const float* V  = (const float*)d_in[2];
    const float* MQ = (const float*)d_in[3];
    const float* MK = (const float*)d_in[4];
    const float* MV = (const float*)d_in[5];
    float* O = (float*)d_out;

    ushort* wsKV = (ushort*)d_ws;
    float*  PO   = (float*)((char*)d_ws + (4u << 20));
    float*  ML   = (float*)((char*)d_ws + (12u << 20));

    prep_kv  <<<dim3(256),  dim3(256), 0, stream>>>(K, V, MV, wsKV);
    attn_main<<<dim3(512),  dim3(256), 0, stream>>>(Q, MQ, MK, wsKV, PO, ML);
    merge_o  <<<dim3(1024), dim3(256), 0, stream>>>(PO, ML, O);
}